// Round 1
// baseline (2397.039 us; speedup 1.0000x reference)
//
#include <hip/hip_runtime.h>

typedef __bf16 bf16x8 __attribute__((ext_vector_type(8)));
typedef float f32x4 __attribute__((ext_vector_type(4)));

#define DEVI __device__ __forceinline__

namespace {
constexpr int cB = 4, cS = 2048, cD = 1024, cH = 2048, cL = 6;
constexpr int cM = cB * cS;                  // 8192 rows
constexpr float cEPS = 1.1920929e-07f;       // torch float32 eps
constexpr int NCH = 16, CHS = cS / NCH;      // scan chunks: 16 x 128
}

DEVI unsigned short f2bf(float f) {
  union { float f; unsigned u; } c; c.f = f;
  const unsigned u = c.u;
  return (unsigned short)((u + 0x7fffu + ((u >> 16) & 1u)) >> 16);  // RNE
}
DEVI float bf2f(unsigned short h) {
  union { unsigned u; float f; } c; c.u = ((unsigned)h) << 16;
  return c.f;
}

DEVI void gld16(const void* g, void* l) {
  __builtin_amdgcn_global_load_lds(
      (__attribute__((address_space(1))) void*)g,
      (__attribute__((address_space(3))) void*)l, 16, 0, 0);
}

union F4 { float4 v; float a[4]; };

// ---------------- embedding gather: xe[bs,:] = emb[x[bs],:] ----------------
__global__ __launch_bounds__(256) void embed_k(const int* __restrict__ x,
    const float* __restrict__ emb, float* __restrict__ xe) {
  const int bs = blockIdx.x;
  const int idx = x[bs];
  const int t = threadIdx.x;
  *(float4*)&xe[(size_t)bs * cD + t * 4] =
      *(const float4*)&emb[(size_t)idx * cD + t * 4];
}

// ------------- depthwise conv (K=3, SAME, zero pad) + bias -> bf16 ----------
__global__ __launch_bounds__(256) void dwconv_k(const float* __restrict__ xe,
    const float* __restrict__ w, const float* __restrict__ bias,
    unsigned short* __restrict__ out) {
  const int bs = blockIdx.x;
  const int s = bs & (cS - 1);
  const int t = threadIdx.x;
  const int d = t * 4;
  const size_t base = (size_t)bs * cD + d;
  F4 x0, xm, xp, vb;
  x0.v = *(const float4*)&xe[base];
  xm.v = make_float4(0.f, 0.f, 0.f, 0.f);
  xp.v = make_float4(0.f, 0.f, 0.f, 0.f);
  if (s > 0) xm.v = *(const float4*)&xe[base - cD];
  if (s < cS - 1) xp.v = *(const float4*)&xe[base + cD];
  vb.v = *(const float4*)&bias[d];
  unsigned short o[4];
#pragma unroll
  for (int j = 0; j < 4; ++j) {
    const float w0 = w[(d + j) * 3 + 0];
    const float w1 = w[(d + j) * 3 + 1];
    const float w2 = w[(d + j) * 3 + 2];
    o[j] = f2bf(xm.a[j] * w0 + x0.a[j] * w1 + xp.a[j] * w2 + vb.a[j]);
  }
  *(ushort4*)&out[base] = make_ushort4(o[0], o[1], o[2], o[3]);
}

// ---------------- RMSNorm row (D=1024) -> bf16 ----------------
__global__ __launch_bounds__(256) void rmsnorm_k(const float* __restrict__ x,
    const float* __restrict__ w, unsigned short* __restrict__ o) {
  const int row = blockIdx.x;
  const int t = threadIdx.x;
  const size_t base = (size_t)row * cD + t * 4;
  F4 v; v.v = *(const float4*)&x[base];
  float ss = v.a[0]*v.a[0] + v.a[1]*v.a[1] + v.a[2]*v.a[2] + v.a[3]*v.a[3];
#pragma unroll
  for (int off = 32; off > 0; off >>= 1) ss += __shfl_down(ss, off, 64);
  __shared__ float red[4];
  if ((t & 63) == 0) red[t >> 6] = ss;
  __syncthreads();
  const float scale = rsqrtf((red[0]+red[1]+red[2]+red[3]) * (1.f/cD) + cEPS);
  F4 wv; wv.v = *(const float4*)&w[t * 4];
  *(ushort4*)&o[base] = make_ushort4(
      f2bf(v.a[0]*scale*wv.a[0]), f2bf(v.a[1]*scale*wv.a[1]),
      f2bf(v.a[2]*scale*wv.a[2]), f2bf(v.a[3]*scale*wv.a[3]));
}

// ---------------- f32 -> bf16 weight convert ----------------
__global__ __launch_bounds__(256) void cvt_k(const float* __restrict__ s,
    unsigned short* __restrict__ d, int n) {
  const int i = (blockIdx.x * 256 + threadIdx.x) * 4;
  if (i >= n) return;
  F4 v; v.v = *(const float4*)&s[i];
  *(ushort4*)&d[i] = make_ushort4(f2bf(v.a[0]), f2bf(v.a[1]),
                                  f2bf(v.a[2]), f2bf(v.a[3]));
}

// ---------------- GEMM: C[M,N] = A[M,K] * W[N,K]^T (+bias, epilogue) -------
// EPI: 0 = f32 store, 1 = f32 residual in-place (+=), 2 = sigmoid->bf16,
//      3 = bf16 store, 4 = exact-gelu->bf16
template<int N, int K, int EPI>
__global__ __launch_bounds__(256) void gemm_bt(
    const unsigned short* __restrict__ A, const unsigned short* __restrict__ W,
    const float* __restrict__ bias, float* __restrict__ Cf,
    unsigned short* __restrict__ Cb) {
  __shared__ unsigned short As[128 * 32];
  __shared__ unsigned short Bs[128 * 32];
  const int t = threadIdx.x;
  const int lane = t & 63;
  const int wave = t >> 6;
  const int m0 = blockIdx.x * 128;
  const int n0 = blockIdx.y * 128;
  const int wm = (wave >> 1) * 64;
  const int wn = (wave & 1) * 64;
  const int fr = lane & 15;           // frag row (A) / col (B) within 16
  const int fk = (lane >> 4) * 8;     // frag k base

  const int arow = t >> 2;            // staging row 0..63 (then +64)
  const int acol = (t & 3) * 8;       // staging k-offset
  const unsigned short* gA = A + (size_t)(m0 + arow) * K + acol;
  const unsigned short* gB = W + (size_t)(n0 + arow) * K + acol;
  unsigned short* lA = As + wave * 512;   // wave-uniform LDS dest
  unsigned short* lB = Bs + wave * 512;

  f32x4 acc[4][4] = {};
  for (int k0 = 0; k0 < K; k0 += 32) {
    gld16(gA + k0, lA);
    gld16(gA + k0 + (size_t)64 * K, lA + 2048);
    gld16(gB + k0, lB);
    gld16(gB + k0 + (size_t)64 * K, lB + 2048);
    __syncthreads();
    bf16x8 fa[4], fb[4];
#pragma unroll
    for (int i = 0; i < 4; ++i) {
      fa[i] = *(const bf16x8*)&As[(wm + i * 16 + fr) * 32 + fk];
      fb[i] = *(const bf16x8*)&Bs[(wn + i * 16 + fr) * 32 + fk];
    }
#pragma unroll
    for (int i = 0; i < 4; ++i)
#pragma unroll
      for (int j = 0; j < 4; ++j)
        acc[i][j] = __builtin_amdgcn_mfma_f32_16x16x32_bf16(
            fa[i], fb[j], acc[i][j], 0, 0, 0);
    __syncthreads();
  }

  const int r0 = m0 + wm + ((lane >> 4) << 2);
  const int c0 = n0 + wn + fr;
#pragma unroll
  for (int i = 0; i < 4; ++i)
#pragma unroll
    for (int j = 0; j < 4; ++j) {
      const int col = c0 + j * 16;
      const float bv = bias[col];
#pragma unroll
      for (int r = 0; r < 4; ++r) {
        const size_t idx = (size_t)(r0 + i * 16 + r) * N + col;
        const float v = acc[i][j][r] + bv;
        if constexpr (EPI == 0) {
          Cf[idx] = v;
        } else if constexpr (EPI == 1) {
          Cf[idx] += v;
        } else if constexpr (EPI == 2) {
          Cb[idx] = f2bf(1.f / (1.f + __expf(-v)));
        } else if constexpr (EPI == 3) {
          Cb[idx] = f2bf(v);
        } else {
          Cb[idx] = f2bf(0.5f * v * (1.f + erff(v * 0.70710678118654752f)));
        }
      }
    }
}

// ---------------- minGRU chunked scan (h = (1-z) h_prev + z htil) ----------
// pass1: per (b, chunk, hpair) compose chunk-local (A, B)
__global__ __launch_bounds__(256) void scan1_k(const unsigned short* __restrict__ z,
    const unsigned short* __restrict__ ht, float* __restrict__ Ac,
    float* __restrict__ Bc) {
  const int tid = blockIdx.x * 256 + threadIdx.x;
  const int hp = (tid & (cH / 2 - 1)) * 2;
  const int ck = (tid / (cH / 2)) & (NCH - 1);
  const int b = tid / ((cH / 2) * NCH);
  const size_t base = ((size_t)b * cS + (size_t)ck * CHS) * cH + hp;
  float a0 = 1.f, s0 = 0.f, a1 = 1.f, s1 = 0.f;
#pragma unroll 4
  for (int s = 0; s < CHS; ++s) {
    const unsigned zz = *(const unsigned*)&z[base + (size_t)s * cH];
    const unsigned hh = *(const unsigned*)&ht[base + (size_t)s * cH];
    const float z0 = bf2f((unsigned short)(zz & 0xffff)), z1 = bf2f((unsigned short)(zz >> 16));
    const float t0 = bf2f((unsigned short)(hh & 0xffff)), t1 = bf2f((unsigned short)(hh >> 16));
    const float aa0 = 1.f - z0, aa1 = 1.f - z1;
    s0 = aa0 * s0 + z0 * t0; a0 *= aa0;
    s1 = aa1 * s1 + z1 * t1; a1 *= aa1;
  }
  const size_t so = ((size_t)b * NCH + ck) * cH + hp;
  *(float2*)&Ac[so] = make_float2(a0, a1);
  *(float2*)&Bc[so] = make_float2(s0, s1);
}

// pass2: per (b,h) scan the 16 chunk summaries; emit chunk prefixes + h_next
__global__ __launch_bounds__(256) void scan2_k(const float* __restrict__ Ac,
    const float* __restrict__ Bc, const float* __restrict__ h_prev,
    float* __restrict__ P, float* __restrict__ hn, int l) {
  const int tid = blockIdx.x * 256 + threadIdx.x;  // B*H
  const int h = tid & (cH - 1);
  const int b = tid >> 11;
  float run = h_prev[((size_t)b * cL + l) * cH + h];
#pragma unroll
  for (int c = 0; c < NCH; ++c) {
    const size_t so = ((size_t)b * NCH + c) * cH + h;
    P[so] = run;
    run = Ac[so] * run + Bc[so];
  }
  hn[((size_t)b * cL + l) * cH + h] = run;
}

// pass3: replay chunk with true prefix; write h (bf16) in-place over htil
__global__ __launch_bounds__(256) void scan3_k(const unsigned short* __restrict__ z,
    unsigned short* __restrict__ ht, const float* __restrict__ P) {
  const int tid = blockIdx.x * 256 + threadIdx.x;
  const int hp = (tid & (cH / 2 - 1)) * 2;
  const int ck = (tid / (cH / 2)) & (NCH - 1);
  const int b = tid / ((cH / 2) * NCH);
  const size_t base = ((size_t)b * cS + (size_t)ck * CHS) * cH + hp;
  const size_t so = ((size_t)b * NCH + ck) * cH + hp;
  const float2 rr = *(const float2*)&P[so];
  float r0 = rr.x, r1 = rr.y;
#pragma unroll 4
  for (int s = 0; s < CHS; ++s) {
    const unsigned zz = *(const unsigned*)&z[base + (size_t)s * cH];
    const unsigned hh = *(const unsigned*)&ht[base + (size_t)s * cH];
    const float z0 = bf2f((unsigned short)(zz & 0xffff)), z1 = bf2f((unsigned short)(zz >> 16));
    const float t0 = bf2f((unsigned short)(hh & 0xffff)), t1 = bf2f((unsigned short)(hh >> 16));
    r0 = (1.f - z0) * r0 + z0 * t0;
    r1 = (1.f - z1) * r1 + z1 * t1;
    *(unsigned*)&ht[base + (size_t)s * cH] =
        (unsigned)f2bf(r0) | ((unsigned)f2bf(r1) << 16);
  }
}

extern "C" void kernel_launch(void* const* d_in, const int* in_sizes, int n_in,
                              void* d_out, int out_size, void* d_ws, size_t ws_size,
                              hipStream_t stream) {
  (void)in_sizes; (void)n_in; (void)out_size; (void)ws_size;
  const int*   x      = (const int*)d_in[0];
  const float* h_prev = (const float*)d_in[1];
  const float* emb    = (const float*)d_in[2];
  const float* cdw_w  = (const float*)d_in[3];
  const float* cdw_b  = (const float*)d_in[4];
  const float* cpw_w  = (const float*)d_in[5];
  const float* cpw_b  = (const float*)d_in[6];
  const float* n1w    = (const float*)d_in[7];
  const float* wzp    = (const float*)d_in[8];
  const float* bzp    = (const float*)d_in[9];
  const float* whp    = (const float*)d_in[10];
  const float* bhp    = (const float*)d_in[11];
  const float* wop    = (const float*)d_in[12];
  const float* bop    = (const float*)d_in[13];
  const float* n2w    = (const float*)d_in[14];
  const float* f1wp   = (const float*)d_in[15];
  const float* f1bp   = (const float*)d_in[16];
  const float* f2wp   = (const float*)d_in[17];
  const float* f2bp   = (const float*)d_in[18];
  const float* nw     = (const float*)d_in[19];
  const float* owp    = (const float*)d_in[20];
  const float* obp    = (const float*)d_in[21];

  float* out_main = (float*)d_out;                  // (B,S,H) f32
  float* out_hn   = out_main + (size_t)cM * cH;     // (B,L,H) f32

  char* p = (char*)d_ws;
  auto alloc = [&](size_t bytes) {
    char* r = p; p += (bytes + 255) & ~(size_t)255; return r;
  };
  float*          xe = (float*)alloc((size_t)cM * cD * 4);          // residual stream
  unsigned short* xn = (unsigned short*)alloc((size_t)cM * cD * 2); // bf16 (conv out / norm out)
  unsigned short* zb = (unsigned short*)alloc((size_t)cM * cH * 2); // z / gelu out
  unsigned short* hb = (unsigned short*)alloc((size_t)cM * cH * 2); // htil -> h
  float* Ac = (float*)alloc((size_t)cB * NCH * cH * 4);
  float* Bc = (float*)alloc((size_t)cB * NCH * cH * 4);
  float* Pr = (float*)alloc((size_t)cB * NCH * cH * 4);
  unsigned short* w_pw = (unsigned short*)alloc((size_t)cD * cD * 2);
  unsigned short* w_z  = (unsigned short*)alloc((size_t)cH * cD * 2);
  unsigned short* w_h  = (unsigned short*)alloc((size_t)cH * cD * 2);
  unsigned short* w_o  = (unsigned short*)alloc((size_t)cD * cH * 2);
  unsigned short* w_f1 = (unsigned short*)alloc((size_t)cH * cD * 2);
  unsigned short* w_f2 = (unsigned short*)alloc((size_t)cD * cH * 2);

  auto cvt = [&](const float* src, unsigned short* dst, size_t n) {
    cvt_k<<<dim3((unsigned)(n / 1024)), 256, 0, stream>>>(src, dst, (int)n);
  };

  embed_k<<<cM, 256, 0, stream>>>(x, emb, xe);

  for (int l = 0; l < cL; ++l) {
    cvt(cpw_w + (size_t)l * cD * cD, w_pw, (size_t)cD * cD);
    cvt(wzp  + (size_t)l * cH * cD, w_z,  (size_t)cH * cD);
    cvt(whp  + (size_t)l * cH * cD, w_h,  (size_t)cH * cD);
    cvt(wop  + (size_t)l * cD * cH, w_o,  (size_t)cD * cH);
    cvt(f1wp + (size_t)l * cH * cD, w_f1, (size_t)cH * cD);
    cvt(f2wp + (size_t)l * cD * cH, w_f2, (size_t)cD * cH);

    // conv block: c = dwconv(xe); xe += pw(c) + b
    dwconv_k<<<cM, 256, 0, stream>>>(xe, cdw_w + (size_t)l * cD * 3,
                                     cdw_b + (size_t)l * cD, xn);
    gemm_bt<cD, cD, 1><<<dim3(cM / 128, cD / 128), 256, 0, stream>>>(
        xn, w_pw, cpw_b + (size_t)l * cD, xe, nullptr);

    // minGRU block
    rmsnorm_k<<<cM, 256, 0, stream>>>(xe, n1w + (size_t)l * cD, xn);
    gemm_bt<cH, cD, 2><<<dim3(cM / 128, cH / 128), 256, 0, stream>>>(
        xn, w_z, bzp + (size_t)l * cH, nullptr, zb);
    gemm_bt<cH, cD, 3><<<dim3(cM / 128, cH / 128), 256, 0, stream>>>(
        xn, w_h, bhp + (size_t)l * cH, nullptr, hb);
    scan1_k<<<cB * NCH * (cH / 2) / 256, 256, 0, stream>>>(zb, hb, Ac, Bc);
    scan2_k<<<cB * cH / 256, 256, 0, stream>>>(Ac, Bc, h_prev, Pr, out_hn, l);
    scan3_k<<<cB * NCH * (cH / 2) / 256, 256, 0, stream>>>(zb, hb, Pr);
    gemm_bt<cD, cH, 1><<<dim3(cM / 128, cD / 128), 256, 0, stream>>>(
        hb, w_o, bop + (size_t)l * cD, xe, nullptr);

    // FFN block
    rmsnorm_k<<<cM, 256, 0, stream>>>(xe, n2w + (size_t)l * cD, xn);
    gemm_bt<cH, cD, 4><<<dim3(cM / 128, cH / 128), 256, 0, stream>>>(
        xn, w_f1, f1bp + (size_t)l * cH, nullptr, zb);
    gemm_bt<cD, cH, 1><<<dim3(cM / 128, cD / 128), 256, 0, stream>>>(
        zb, w_f2, f2bp + (size_t)l * cD, xe, nullptr);
  }

  rmsnorm_k<<<cM, 256, 0, stream>>>(xe, nw, xn);
  cvt(owp, w_z, (size_t)cH * cD);
  gemm_bt<cH, cD, 0><<<dim3(cM / 128, cH / 128), 256, 0, stream>>>(
      xn, w_z, obp, out_main, nullptr);
}

// Round 2
// 2358.871 us; speedup vs baseline: 1.0162x; 1.0162x over previous
//
#include <hip/hip_runtime.h>

typedef __bf16 bf16x8 __attribute__((ext_vector_type(8)));
typedef float f32x4 __attribute__((ext_vector_type(4)));

#define DEVI __device__ __forceinline__

namespace {
constexpr int cB = 4, cS = 2048, cD = 1024, cH = 2048, cL = 6;
constexpr int cM = cB * cS;                  // 8192 rows
constexpr float cEPS = 1.1920929e-07f;       // torch float32 eps
constexpr int NCH = 16, CHS = cS / NCH;      // scan chunks: 16 x 128
}

DEVI unsigned short f2bf(float f) {
  union { float f; unsigned u; } c; c.f = f;
  const unsigned u = c.u;
  return (unsigned short)((u + 0x7fffu + ((u >> 16) & 1u)) >> 16);  // RNE
}
DEVI float bf2f(unsigned short h) {
  union { unsigned u; float f; } c; c.u = ((unsigned)h) << 16;
  return c.f;
}

DEVI void gld16(const void* g, void* l) {
  __builtin_amdgcn_global_load_lds(
      (__attribute__((address_space(1))) void*)g,
      (__attribute__((address_space(3))) void*)l, 16, 0, 0);
}

union F4 { float4 v; float a[4]; };

// ---------------- embedding gather ----------------
__global__ __launch_bounds__(256) void embed_k(const int* __restrict__ x,
    const float* __restrict__ emb, float* __restrict__ xe) {
  const int bs = blockIdx.x;
  const int idx = x[bs];
  const int t = threadIdx.x;
  *(float4*)&xe[(size_t)bs * cD + t * 4] =
      *(const float4*)&emb[(size_t)idx * cD + t * 4];
}

// ------------- depthwise conv (K=3, SAME) + bias -> bf16 ----------
__global__ __launch_bounds__(256) void dwconv_k(const float* __restrict__ xe,
    const float* __restrict__ w, const float* __restrict__ bias,
    unsigned short* __restrict__ out) {
  const int bs = blockIdx.x;
  const int s = bs & (cS - 1);
  const int t = threadIdx.x;
  const int d = t * 4;
  const size_t base = (size_t)bs * cD + d;
  F4 x0, xm, xp, vb;
  x0.v = *(const float4*)&xe[base];
  xm.v = make_float4(0.f, 0.f, 0.f, 0.f);
  xp.v = make_float4(0.f, 0.f, 0.f, 0.f);
  if (s > 0) xm.v = *(const float4*)&xe[base - cD];
  if (s < cS - 1) xp.v = *(const float4*)&xe[base + cD];
  vb.v = *(const float4*)&bias[d];
  unsigned short o[4];
#pragma unroll
  for (int j = 0; j < 4; ++j) {
    const float w0 = w[(d + j) * 3 + 0];
    const float w1 = w[(d + j) * 3 + 1];
    const float w2 = w[(d + j) * 3 + 2];
    o[j] = f2bf(xm.a[j] * w0 + x0.a[j] * w1 + xp.a[j] * w2 + vb.a[j]);
  }
  *(ushort4*)&out[base] = make_ushort4(o[0], o[1], o[2], o[3]);
}

// ---------------- RMSNorm row (D=1024) -> bf16 ----------------
__global__ __launch_bounds__(256) void rmsnorm_k(const float* __restrict__ x,
    const float* __restrict__ w, unsigned short* __restrict__ o) {
  const int row = blockIdx.x;
  const int t = threadIdx.x;
  const size_t base = (size_t)row * cD + t * 4;
  F4 v; v.v = *(const float4*)&x[base];
  float ss = v.a[0]*v.a[0] + v.a[1]*v.a[1] + v.a[2]*v.a[2] + v.a[3]*v.a[3];
#pragma unroll
  for (int off = 32; off > 0; off >>= 1) ss += __shfl_down(ss, off, 64);
  __shared__ float red[4];
  if ((t & 63) == 0) red[t >> 6] = ss;
  __syncthreads();
  const float scale = rsqrtf((red[0]+red[1]+red[2]+red[3]) * (1.f/cD) + cEPS);
  F4 wv; wv.v = *(const float4*)&w[t * 4];
  *(ushort4*)&o[base] = make_ushort4(
      f2bf(v.a[0]*scale*wv.a[0]), f2bf(v.a[1]*scale*wv.a[1]),
      f2bf(v.a[2]*scale*wv.a[2]), f2bf(v.a[3]*scale*wv.a[3]));
}

// ---------------- f32 -> bf16 convert ----------------
__global__ __launch_bounds__(256) void cvt_k(const float* __restrict__ s,
    unsigned short* __restrict__ d, int n) {
  const int i = (blockIdx.x * 256 + threadIdx.x) * 4;
  if (i >= n) return;
  F4 v; v.v = *(const float4*)&s[i];
  *(ushort4*)&d[i] = make_ushort4(f2bf(v.a[0]), f2bf(v.a[1]),
                                  f2bf(v.a[2]), f2bf(v.a[3]));
}

// ---------------- m97 GEMM: C[M,N] = A * W^T (+bias, epilogue) -------------
// EPI: 1 = f32 residual in-place (+=)
template<int N, int K, int EPI>
__global__ __launch_bounds__(256) void gemm_bt(
    const unsigned short* __restrict__ A, const unsigned short* __restrict__ W,
    const float* __restrict__ bias, float* __restrict__ Cf,
    unsigned short* __restrict__ Cb) {
  __shared__ unsigned short As[128 * 32];
  __shared__ unsigned short Bs[128 * 32];
  const int t = threadIdx.x;
  const int lane = t & 63;
  const int wave = t >> 6;
  const int m0 = blockIdx.x * 128;
  const int n0 = blockIdx.y * 128;
  const int wm = (wave >> 1) * 64;
  const int wn = (wave & 1) * 64;
  const int fr = lane & 15;
  const int fk = (lane >> 4) * 8;

  const int arow = t >> 2;
  const int acol = (t & 3) * 8;
  const unsigned short* gA = A + (size_t)(m0 + arow) * K + acol;
  const unsigned short* gB = W + (size_t)(n0 + arow) * K + acol;
  unsigned short* lA = As + wave * 512;
  unsigned short* lB = Bs + wave * 512;

  f32x4 acc[4][4] = {};
  for (int k0 = 0; k0 < K; k0 += 32) {
    gld16(gA + k0, lA);
    gld16(gA + k0 + (size_t)64 * K, lA + 2048);
    gld16(gB + k0, lB);
    gld16(gB + k0 + (size_t)64 * K, lB + 2048);
    __syncthreads();
    bf16x8 fa[4], fb[4];
#pragma unroll
    for (int i = 0; i < 4; ++i) {
      fa[i] = *(const bf16x8*)&As[(wm + i * 16 + fr) * 32 + fk];
      fb[i] = *(const bf16x8*)&Bs[(wn + i * 16 + fr) * 32 + fk];
    }
#pragma unroll
    for (int i = 0; i < 4; ++i)
#pragma unroll
      for (int j = 0; j < 4; ++j)
        acc[i][j] = __builtin_amdgcn_mfma_f32_16x16x32_bf16(
            fa[i], fb[j], acc[i][j], 0, 0, 0);
    __syncthreads();
  }

  const int r0 = m0 + wm + ((lane >> 4) << 2);
  const int c0 = n0 + wn + fr;
#pragma unroll
  for (int i = 0; i < 4; ++i)
#pragma unroll
    for (int j = 0; j < 4; ++j) {
      const int col = c0 + j * 16;
      const float bv = bias[col];
#pragma unroll
      for (int r = 0; r < 4; ++r) {
        const size_t idx = (size_t)(r0 + i * 16 + r) * N + col;
        const float v = acc[i][j][r] + bv;
        if constexpr (EPI == 1) {
          Cf[idx] += v;
        } else {
          Cf[idx] = v;
        }
      }
    }
}

// ============ 256x256 8-phase GEMM (T2 swizzle + T3/T4 counted vmcnt + T5) ==
// C[M,N] = A[M,K] * W[N,K]^T, W split at NS: rows [0,NS) from W0 (bias0),
// rows [NS,N) from W1 (bias1). EPI: 0 = f32->Cf; 4 = gelu->Cb;
// 5 = split: sigmoid->Cb (col<NS), plain->Cb2 (col>=NS). Output width per
// part: NS / N-NS.
#define RDA(BUF, MH)                                                        \
  _Pragma("unroll") for (int mf = 0; mf < 4; ++mf)                          \
  _Pragma("unroll") for (int kk = 0; kk < 2; ++kk)                          \
      a[mf * 2 + kk] = *(const bf16x8*)&lds[(BUF)*16384 + aB + (MH)*4096 +  \
                                            mf * 1024 + kk * 32];

#define RDB(BUF)                                                            \
  _Pragma("unroll") for (int q = 0; q < 4; ++q)                             \
  _Pragma("unroll") for (int kk = 0; kk < 2; ++kk)                          \
      b[q >> 1][(q & 1) * 2 + kk] =                                         \
          *(const bf16x8*)&lds[(BUF)*16384 + bB + q * 1024 + kk * 32];

#define MMQ(MH, NH)                                                         \
  _Pragma("unroll") for (int mf = 0; mf < 4; ++mf)                          \
  _Pragma("unroll") for (int nf = 0; nf < 2; ++nf)                          \
  _Pragma("unroll") for (int kk = 0; kk < 2; ++kk)                          \
      acc[(MH)*4 + mf][(NH)*2 + nf] = __builtin_amdgcn_mfma_f32_16x16x32_bf16( \
          a[mf * 2 + kk], b[NH][nf * 2 + kk], acc[(MH)*4 + mf][(NH)*2 + nf],  \
          0, 0, 0);

#define PH_SYNC()                                                           \
  __builtin_amdgcn_s_barrier();                                             \
  asm volatile("s_waitcnt lgkmcnt(0)" ::: "memory");                        \
  __builtin_amdgcn_sched_barrier(0);                                        \
  __builtin_amdgcn_s_setprio(1)

#define PH_END()                                                            \
  __builtin_amdgcn_s_setprio(0);                                            \
  __builtin_amdgcn_s_barrier()

// Tile TI in buffer BUF; OBUF = BUF^1. Stage slots (derived, see analysis):
// ph1 -> (TI+1, A-half1) into OBUF; ph2 -> (TI+2, B-half0) into BUF;
// ph3 -> (TI+2, B-half1) into BUF; ph4 -> (TI+2, A-half0) into BUF + vmcnt(6).
#define TILE_PHASES(TI, BUF, OBUF)                                          \
  {                                                                         \
    RDA(BUF, 0); RDB(BUF);                                                  \
    { const int n1 = (TI) + 1;                                              \
      stA((n1 < NT) ? n1 : 0, 1, (n1 < NT) ? ldsA(OBUF, 1) : ldsDummy); }   \
    asm volatile("s_waitcnt lgkmcnt(8)" ::: "memory");                      \
    PH_SYNC(); MMQ(0, 0); PH_END();                                         \
    { const int n2 = (TI) + 2;                                              \
      stB((n2 < NT) ? n2 : 0, 0, (n2 < NT) ? ldsB(BUF, 0) : ldsDummy); }    \
    PH_SYNC(); MMQ(0, 1); PH_END();                                         \
    RDA(BUF, 1);                                                            \
    { const int n2 = (TI) + 2;                                              \
      stB((n2 < NT) ? n2 : 0, 1, (n2 < NT) ? ldsB(BUF, 1) : ldsDummy); }    \
    PH_SYNC(); MMQ(1, 1); PH_END();                                         \
    { const int n2 = (TI) + 2;                                              \
      stA((n2 < NT) ? n2 : 0, 0, (n2 < NT) ? ldsA(BUF, 0) : ldsDummy); }    \
    asm volatile("s_waitcnt vmcnt(6)" ::: "memory");                        \
    PH_SYNC(); MMQ(1, 0); PH_END();                                         \
  }

template<int N, int K, int EPI, int NS>
__global__ __launch_bounds__(512, 2) void gemm8p(
    const unsigned short* __restrict__ A,
    const unsigned short* __restrict__ W0,
    const unsigned short* __restrict__ W1,
    const float* __restrict__ bias0, const float* __restrict__ bias1,
    float* __restrict__ Cf, unsigned short* __restrict__ Cb,
    unsigned short* __restrict__ Cb2) {
  static_assert(K % 128 == 0, "NT must be even");
  constexpr int NT = K / 64;
  // LDS map (ushort units): A[buf][half] at buf*16384 + half*8192;
  // B at +32768; dummy tail-stage region at 65536 (16 KiB). Total 144 KiB.
  __shared__ unsigned short lds[73728];
  const int t = threadIdx.x;
  const int lane = t & 63;
  const int wave = t >> 6;
  const int wr = wave >> 2;   // 0..1  (M half)
  const int wc = wave & 3;    // 0..3  (N quarter)
  const int m0 = blockIdx.x * 256;
  const int n0 = blockIdx.y * 256;

  const bool zpart = (n0 < NS);
  const unsigned short* Wp = zpart ? W0 : W1;
  const int nw0 = zpart ? n0 : n0 - NS;
  const float* bp = zpart ? bias0 : bias1;
  const int CW = zpart ? NS : (N - NS);

  // --- staging addressing (pre-swizzled global source; linear LDS dest) ---
  const int srow = t >> 3;                                  // 0..63
  const int scol = ((t & 7) * 8) ^ (((t >> 5) & 1) << 4);   // st_16x32 swz
  const unsigned short* gA = A  + (size_t)(m0 + srow) * K + scol;
  const unsigned short* gB = Wp + (size_t)(nw0 + srow) * K + scol;
  const int ldsw = wave * 512;

  auto ldsA = [&](int buf, int h) -> unsigned short* {
    return (unsigned short*)&lds[buf * 16384 + h * 8192 + ldsw];
  };
  auto ldsB = [&](int buf, int h) -> unsigned short* {
    return (unsigned short*)&lds[32768 + buf * 16384 + h * 8192 + ldsw];
  };
  unsigned short* ldsDummy = (unsigned short*)&lds[65536 + ldsw];
  auto stA = [&](int tile, int h, unsigned short* dst) {
    const unsigned short* s = gA + (size_t)(h * 128) * K + tile * 64;
    gld16(s, dst);
    gld16(s + (size_t)64 * K, dst + 4096);
  };
  auto stB = [&](int tile, int h, unsigned short* dst) {
    const unsigned short* s = gB + (size_t)(h * 128) * K + tile * 64;
    gld16(s, dst);
    gld16(s + (size_t)64 * K, dst + 4096);
  };

  // --- fragment read addressing (swizzled ds_read) ---
  const int sx = ((lane >> 2) & 1) << 4;     // row-bit2 -> col-bit4 XOR
  const int aoff = (lane & 15) * 64 + (((lane >> 4) * 8) ^ sx);
  const int aB = wr * 8192 + aoff;
  const int bB = 32768 + (wc >> 1) * 8192 + (wc & 1) * 4096 + aoff;

  bf16x8 a[8];
  bf16x8 b[2][4];
  f32x4 acc[8][4] = {};

  // --- prologue: 7 half-tiles, leave last 3 in flight ---
  stB(0, 0, ldsB(0, 0)); stB(0, 1, ldsB(0, 1));
  stA(0, 0, ldsA(0, 0)); stA(0, 1, ldsA(0, 1));
  stB(1, 0, ldsB(1, 0)); stB(1, 1, ldsB(1, 1));
  stA(1, 0, ldsA(1, 0));
  asm volatile("s_waitcnt vmcnt(6)" ::: "memory");
  __builtin_amdgcn_s_barrier();

  for (int tp = 0; tp < NT / 2; ++tp) {
    const int t0 = 2 * tp;
    TILE_PHASES(t0, 0, 1);
    TILE_PHASES(t0 + 1, 1, 0);
  }

  // --- epilogue ---
  float* cf = Cf;
  unsigned short* cb = zpart ? Cb : Cb2;
  const int r0 = m0 + wr * 128 + ((lane >> 4) << 2);
  const int c0 = nw0 + wc * 64 + (lane & 15);
#pragma unroll
  for (int mfg = 0; mfg < 8; ++mfg) {
#pragma unroll
    for (int nfg = 0; nfg < 4; ++nfg) {
      const int col = c0 + nfg * 16;
      const float bv = bp[col];
#pragma unroll
      for (int r = 0; r < 4; ++r) {
        const size_t idx = (size_t)(r0 + mfg * 16 + r) * CW + col;
        const float v = acc[mfg][nfg][r] + bv;
        if constexpr (EPI == 0) {
          cf[idx] = v;
        } else if constexpr (EPI == 4) {
          cb[idx] = f2bf(0.5f * v * (1.f + erff(v * 0.70710678118654752f)));
        } else {  // EPI == 5
          if (zpart) cb[idx] = f2bf(1.f / (1.f + __expf(-v)));
          else       cb[idx] = f2bf(v);
        }
      }
    }
  }
}

// ---------------- minGRU chunked scan ----------
__global__ __launch_bounds__(256) void scan1_k(const unsigned short* __restrict__ z,
    const unsigned short* __restrict__ ht, float* __restrict__ Ac,
    float* __restrict__ Bc) {
  const int tid = blockIdx.x * 256 + threadIdx.x;
  const int hp = (tid & (cH / 2 - 1)) * 2;
  const int ck = (tid / (cH / 2)) & (NCH - 1);
  const int b = tid / ((cH / 2) * NCH);
  const size_t base = ((size_t)b * cS + (size_t)ck * CHS) * cH + hp;
  float a0 = 1.f, s0 = 0.f, a1 = 1.f, s1 = 0.f;
#pragma unroll 4
  for (int s = 0; s < CHS; ++s) {
    const unsigned zz = *(const unsigned*)&z[base + (size_t)s * cH];
    const unsigned hh = *(const unsigned*)&ht[base + (size_t)s * cH];
    const float z0 = bf2f((unsigned short)(zz & 0xffff)), z1 = bf2f((unsigned short)(zz >> 16));
    const float t0 = bf2f((unsigned short)(hh & 0xffff)), t1 = bf2f((unsigned short)(hh >> 16));
    const float aa0 = 1.f - z0, aa1 = 1.f - z1;
    s0 = aa0 * s0 + z0 * t0; a0 *= aa0;
    s1 = aa1 * s1 + z1 * t1; a1 *= aa1;
  }
  const size_t so = ((size_t)b * NCH + ck) * cH + hp;
  *(float2*)&Ac[so] = make_float2(a0, a1);
  *(float2*)&Bc[so] = make_float2(s0, s1);
}

__global__ __launch_bounds__(256) void scan2_k(const float* __restrict__ Ac,
    const float* __restrict__ Bc, const float* __restrict__ h_prev,
    float* __restrict__ P, float* __restrict__ hn, int l) {
  const int tid = blockIdx.x * 256 + threadIdx.x;  // B*H
  const int h = tid & (cH - 1);
  const int b = tid >> 11;
  float run = h_prev[((size_t)b * cL + l) * cH + h];
#pragma unroll
  for (int c = 0; c < NCH; ++c) {
    const size_t so = ((size_t)b * NCH + c) * cH + h;
    P[so] = run;
    run = Ac[so] * run + Bc[so];
  }
  hn[((size_t)b * cL + l) * cH + h] = run;
}

__global__ __launch_bounds__(256) void scan3_k(const unsigned short* __restrict__ z,
    unsigned short* __restrict__ ht, const float* __restrict__ P) {
  const int tid = blockIdx.x * 256 + threadIdx.x;
  const int hp = (tid & (cH / 2 - 1)) * 2;
  const int ck = (tid / (cH / 2)) & (NCH - 1);
  const int b = tid / ((cH / 2) * NCH);
  const size_t base = ((size_t)b * cS + (size_t)ck * CHS) * cH + hp;
  const size_t so = ((size_t)b * NCH + ck) * cH + hp;
  const float2 rr = *(const float2*)&P[so];
  float r0 = rr.x, r1 = rr.y;
#pragma unroll 4
  for (int s = 0; s < CHS; ++s) {
    const unsigned zz = *(const unsigned*)&z[base + (size_t)s * cH];
    const unsigned hh = *(const unsigned*)&ht[base + (size_t)s * cH];
    const float z0 = bf2f((unsigned short)(zz & 0xffff)), z1 = bf2f((unsigned short)(zz >> 16));
    const float t0 = bf2f((unsigned short)(hh & 0xffff)), t1 = bf2f((unsigned short)(hh >> 16));
    r0 = (1.f - z0) * r0 + z0 * t0;
    r1 = (1.f - z1) * r1 + z1 * t1;
    *(unsigned*)&ht[base + (size_t)s * cH] =
        (unsigned)f2bf(r0) | ((unsigned)f2bf(r1) << 16);
  }
}

extern "C" void kernel_launch(void* const* d_in, const int* in_sizes, int n_in,
                              void* d_out, int out_size, void* d_ws, size_t ws_size,
                              hipStream_t stream) {
  (void)in_sizes; (void)n_in; (void)out_size; (void)ws_size;
  const int*   x      = (const int*)d_in[0];
  const float* h_prev = (const float*)d_in[1];
  const float* emb    = (const float*)d_in[2];
  const float* cdw_w  = (const float*)d_in[3];
  const float* cdw_b  = (const float*)d_in[4];
  const float* cpw_w  = (const float*)d_in[5];
  const float* cpw_b  = (const float*)d_in[6];
  const float* n1w    = (const float*)d_in[7];
  const float* wzp    = (const float*)d_in[8];
  const float* bzp    = (const float*)d_in[9];
  const float* whp    = (const float*)d_in[10];
  const float* bhp    = (const float*)d_in[11];
  const float* wop    = (const float*)d_in[12];
  const float* bop    = (const float*)d_in[13];
  const float* n2w    = (const float*)d_in[14];
  const float* f1wp   = (const float*)d_in[15];
  const float* f1bp   = (const float*)d_in[16];
  const float* f2wp   = (const float*)d_in[17];
  const float* f2bp   = (const float*)d_in[18];
  const float* nw     = (const float*)d_in[19];
  const float* owp    = (const float*)d_in[20];
  const float* obp    = (const float*)d_in[21];

  float* out_main = (float*)d_out;                  // (B,S,H) f32
  float* out_hn   = out_main + (size_t)cM * cH;     // (B,L,H) f32

  char* p = (char*)d_ws;
  auto alloc = [&](size_t bytes) {
    char* r = p; p += (bytes + 255) & ~(size_t)255; return r;
  };
  float*          xe = (float*)alloc((size_t)cM * cD * 4);
  unsigned short* xn = (unsigned short*)alloc((size_t)cM * cD * 2);
  unsigned short* zb = (unsigned short*)alloc((size_t)cM * cH * 2);
  unsigned short* hb = (unsigned short*)alloc((size_t)cM * cH * 2);
  float* Ac = (float*)alloc((size_t)cB * NCH * cH * 4);
  float* Bc = (float*)alloc((size_t)cB * NCH * cH * 4);
  float* Pr = (float*)alloc((size_t)cB * NCH * cH * 4);
  // all-layer bf16 weights (hoisted conversion)
  unsigned short* w_pw = (unsigned short*)alloc((size_t)cL * cD * cD * 2);
  unsigned short* w_z  = (unsigned short*)alloc((size_t)cL * cH * cD * 2);
  unsigned short* w_h  = (unsigned short*)alloc((size_t)cL * cH * cD * 2);
  unsigned short* w_o  = (unsigned short*)alloc((size_t)cL * cD * cH * 2);
  unsigned short* w_f1 = (unsigned short*)alloc((size_t)cL * cH * cD * 2);
  unsigned short* w_f2 = (unsigned short*)alloc((size_t)cL * cD * cH * 2);
  unsigned short* w_ow = (unsigned short*)alloc((size_t)cH * cD * 2);

  auto cvt = [&](const float* src, unsigned short* dst, size_t n) {
    cvt_k<<<dim3((unsigned)(n / 1024)), 256, 0, stream>>>(src, dst, (int)n);
  };

  // hoisted whole-tensor weight conversion (7 dispatches)
  cvt(cpw_w, w_pw, (size_t)cL * cD * cD);
  cvt(wzp,  w_z,  (size_t)cL * cH * cD);
  cvt(whp,  w_h,  (size_t)cL * cH * cD);
  cvt(wop,  w_o,  (size_t)cL * cD * cH);
  cvt(f1wp, w_f1, (size_t)cL * cH * cD);
  cvt(f2wp, w_f2, (size_t)cL * cD * cH);
  cvt(owp,  w_ow, (size_t)cH * cD);

  embed_k<<<cM, 256, 0, stream>>>(x, emb, xe);

  for (int l = 0; l < cL; ++l) {
    const size_t oDD = (size_t)l * cD * cD, oHD = (size_t)l * cH * cD;

    // conv block: xe += pw(dwconv(xe)) + b
    dwconv_k<<<cM, 256, 0, stream>>>(xe, cdw_w + (size_t)l * cD * 3,
                                     cdw_b + (size_t)l * cD, xn);
    gemm_bt<cD, cD, 1><<<dim3(cM / 128, cD / 128), 256, 0, stream>>>(
        xn, w_pw + oDD, cpw_b + (size_t)l * cD, xe, nullptr);

    // minGRU block: merged z|htil GEMM (N=4096, block-uniform split)
    rmsnorm_k<<<cM, 256, 0, stream>>>(xe, n1w + (size_t)l * cD, xn);
    gemm8p<2 * cH, cD, 5, cH><<<dim3(cM / 256, 2 * cH / 256), 512, 0, stream>>>(
        xn, w_z + oHD, w_h + oHD, bzp + (size_t)l * cH, bhp + (size_t)l * cH,
        nullptr, zb, hb);
    scan1_k<<<cB * NCH * (cH / 2) / 256, 256, 0, stream>>>(zb, hb, Ac, Bc);
    scan2_k<<<cB * cH / 256, 256, 0, stream>>>(Ac, Bc, h_prev, Pr, out_hn, l);
    scan3_k<<<cB * NCH * (cH / 2) / 256, 256, 0, stream>>>(zb, hb, Pr);
    gemm_bt<cD, cH, 1><<<dim3(cM / 128, cD / 128), 256, 0, stream>>>(
        hb, w_o + oHD, bop + (size_t)l * cD, xe, nullptr);

    // FFN block
    rmsnorm_k<<<cM, 256, 0, stream>>>(xe, n2w + (size_t)l * cD, xn);
    gemm8p<cH, cD, 4, cH><<<dim3(cM / 256, cH / 256), 512, 0, stream>>>(
        xn, w_f1 + oHD, w_f1 + oHD, f1bp + (size_t)l * cH, f1bp + (size_t)l * cH,
        nullptr, zb, zb);
    gemm_bt<cD, cH, 1><<<dim3(cM / 128, cD / 128), 256, 0, stream>>>(
        zb, w_f2 + oHD, f2bp + (size_t)l * cD, xe, nullptr);
  }

  rmsnorm_k<<<cM, 256, 0, stream>>>(xe, nw, xn);
  gemm8p<cH, cD, 0, cH><<<dim3(cM / 256, cH / 256), 512, 0, stream>>>(
      xn, w_ow, w_ow, obp, obp, out_main, nullptr, nullptr);
}